// Round 1
// baseline (1501.975 us; speedup 1.0000x reference)
//
#include <hip/hip_runtime.h>
#include <cstdint>

#define HD   12     // num heads
#define TSEQ 2048   // sequence length
#define DM   768    // d_model
#define DK   64     // head dim
#define BATCH 2

// ---------------------------------------------------------------------------
// NT GEMM: C[m][n] = alpha * sum_k A[m][k] * Bw[n][k]   (torch Linear layout)
// grid (M/64, N/64), 64 threads/block (1 wave), each thread computes 8x8.
// LDS rows padded to 13 floats: 8-row-stride reads land 2-way on banks (free).
// ---------------------------------------------------------------------------
__global__ __launch_bounds__(64) void gemm_nt(
    const float* __restrict__ A, const float* __restrict__ Bw,
    float* __restrict__ C, int K, int lda, int ldb, int ldc, float alpha)
{
    __shared__ float As[64][13];
    __shared__ float Bs[64][13];
    const int t = threadIdx.x;
    const int tx = t & 7, ty = t >> 3;
    const int m0 = blockIdx.x * 64, n0 = blockIdx.y * 64;
    const float* Arow = A + (size_t)(m0 + t) * lda;
    const float* Brow = Bw + (size_t)(n0 + t) * ldb;

    float acc[8][8];
    #pragma unroll
    for (int i = 0; i < 8; ++i)
        #pragma unroll
        for (int j = 0; j < 8; ++j) acc[i][j] = 0.f;

    for (int k0 = 0; k0 < K; k0 += 8) {
        float4 a0 = *(const float4*)(Arow + k0);
        float4 a1 = *(const float4*)(Arow + k0 + 4);
        float4 b0 = *(const float4*)(Brow + k0);
        float4 b1 = *(const float4*)(Brow + k0 + 4);
        __syncthreads();
        As[t][0] = a0.x; As[t][1] = a0.y; As[t][2] = a0.z; As[t][3] = a0.w;
        As[t][4] = a1.x; As[t][5] = a1.y; As[t][6] = a1.z; As[t][7] = a1.w;
        Bs[t][0] = b0.x; Bs[t][1] = b0.y; Bs[t][2] = b0.z; Bs[t][3] = b0.w;
        Bs[t][4] = b1.x; Bs[t][5] = b1.y; Bs[t][6] = b1.z; Bs[t][7] = b1.w;
        __syncthreads();
        #pragma unroll
        for (int kk = 0; kk < 8; ++kk) {
            float a[8], b[8];
            #pragma unroll
            for (int i = 0; i < 8; ++i) a[i] = As[ty * 8 + i][kk];
            #pragma unroll
            for (int j = 0; j < 8; ++j) b[j] = Bs[tx * 8 + j][kk];
            #pragma unroll
            for (int i = 0; i < 8; ++i)
                #pragma unroll
                for (int j = 0; j < 8; ++j)
                    acc[i][j] = fmaf(a[i], b[j], acc[i][j]);
        }
    }
    #pragma unroll
    for (int i = 0; i < 8; ++i) {
        float* crow = C + (size_t)(m0 + ty * 8 + i) * ldc + n0 + tx * 8;
        float4 o0 = make_float4(acc[i][0] * alpha, acc[i][1] * alpha,
                                acc[i][2] * alpha, acc[i][3] * alpha);
        float4 o1 = make_float4(acc[i][4] * alpha, acc[i][5] * alpha,
                                acc[i][6] * alpha, acc[i][7] * alpha);
        *(float4*)crow = o0;
        *(float4*)(crow + 4) = o1;
    }
}

// ---------------------------------------------------------------------------
// Scores: S[b,h,q,k] = (1/8) * sum_d Qp[b,q,h*64+d] * Kp[b,k,h*64+d]
// grid (32, 32, B*H), 64 threads, 8x8/thread, written unnormalized to wts.
// ---------------------------------------------------------------------------
__global__ __launch_bounds__(64) void attn_scores(
    const float* __restrict__ Qp, const float* __restrict__ Kp,
    float* __restrict__ Wt)
{
    const int z = blockIdx.z, b = z / HD, h = z % HD;
    const float* A  = Qp + ((size_t)b * TSEQ) * DM + h * DK;
    const float* Bk = Kp + ((size_t)b * TSEQ) * DM + h * DK;
    float* C = Wt + (size_t)z * TSEQ * TSEQ;

    __shared__ float As[64][13];
    __shared__ float Bs[64][13];
    const int t = threadIdx.x, tx = t & 7, ty = t >> 3;
    const int m0 = blockIdx.x * 64, n0 = blockIdx.y * 64;
    const float* Arow = A  + (size_t)(m0 + t) * DM;
    const float* Brow = Bk + (size_t)(n0 + t) * DM;

    float acc[8][8];
    #pragma unroll
    for (int i = 0; i < 8; ++i)
        #pragma unroll
        for (int j = 0; j < 8; ++j) acc[i][j] = 0.f;

    for (int k0 = 0; k0 < DK; k0 += 8) {
        float4 a0 = *(const float4*)(Arow + k0);
        float4 a1 = *(const float4*)(Arow + k0 + 4);
        float4 b0 = *(const float4*)(Brow + k0);
        float4 b1 = *(const float4*)(Brow + k0 + 4);
        __syncthreads();
        As[t][0] = a0.x; As[t][1] = a0.y; As[t][2] = a0.z; As[t][3] = a0.w;
        As[t][4] = a1.x; As[t][5] = a1.y; As[t][6] = a1.z; As[t][7] = a1.w;
        Bs[t][0] = b0.x; Bs[t][1] = b0.y; Bs[t][2] = b0.z; Bs[t][3] = b0.w;
        Bs[t][4] = b1.x; Bs[t][5] = b1.y; Bs[t][6] = b1.z; Bs[t][7] = b1.w;
        __syncthreads();
        #pragma unroll
        for (int kk = 0; kk < 8; ++kk) {
            float a[8], b[8];
            #pragma unroll
            for (int i = 0; i < 8; ++i) a[i] = As[ty * 8 + i][kk];
            #pragma unroll
            for (int j = 0; j < 8; ++j) b[j] = Bs[tx * 8 + j][kk];
            #pragma unroll
            for (int i = 0; i < 8; ++i)
                #pragma unroll
                for (int j = 0; j < 8; ++j)
                    acc[i][j] = fmaf(a[i], b[j], acc[i][j]);
        }
    }
    const float alpha = 0.125f;  // 1/sqrt(64)
    #pragma unroll
    for (int i = 0; i < 8; ++i) {
        float* crow = C + (size_t)(m0 + ty * 8 + i) * TSEQ + n0 + tx * 8;
        float4 o0 = make_float4(acc[i][0] * alpha, acc[i][1] * alpha,
                                acc[i][2] * alpha, acc[i][3] * alpha);
        float4 o1 = make_float4(acc[i][4] * alpha, acc[i][5] * alpha,
                                acc[i][6] * alpha, acc[i][7] * alpha);
        *(float4*)crow = o0;
        *(float4*)(crow + 4) = o1;
    }
}

// ---------------------------------------------------------------------------
// In-place row softmax over 2048-length rows. One block (256 thr) per row.
// ---------------------------------------------------------------------------
__global__ __launch_bounds__(256) void softmax_rows(float* __restrict__ Wt)
{
    float* p = Wt + (size_t)blockIdx.x * TSEQ;
    const int t = threadIdx.x;
    float v[8];
    float m = -3.4e38f;
    #pragma unroll
    for (int i = 0; i < 8; ++i) { v[i] = p[t + 256 * i]; m = fmaxf(m, v[i]); }
    #pragma unroll
    for (int off = 32; off > 0; off >>= 1) m = fmaxf(m, __shfl_down(m, off));
    __shared__ float redm[4];
    __shared__ float reds[4];
    const int lane = t & 63, wid = t >> 6;
    if (lane == 0) redm[wid] = m;
    __syncthreads();
    m = fmaxf(fmaxf(redm[0], redm[1]), fmaxf(redm[2], redm[3]));
    float s = 0.f;
    #pragma unroll
    for (int i = 0; i < 8; ++i) { v[i] = __expf(v[i] - m); s += v[i]; }
    #pragma unroll
    for (int off = 32; off > 0; off >>= 1) s += __shfl_down(s, off);
    if (lane == 0) reds[wid] = s;
    __syncthreads();
    s = reds[0] + reds[1] + reds[2] + reds[3];
    const float inv = 1.f / s;
    #pragma unroll
    for (int i = 0; i < 8; ++i) p[t + 256 * i] = v[i] * inv;
}

// ---------------------------------------------------------------------------
// PV: ctx[b, q, h*64+d] = sum_k W[b,h,q,k] * Vp[b,k,h*64+d]   (NN GEMM)
// grid (32, 1, B*H), 64 threads, 8x8/thread. K = 2048.
// ---------------------------------------------------------------------------
__global__ __launch_bounds__(64) void attn_pv(
    const float* __restrict__ Wt, const float* __restrict__ Vp,
    float* __restrict__ ctx)
{
    const int z = blockIdx.z, b = z / HD, h = z % HD;
    const float* A = Wt + (size_t)z * TSEQ * TSEQ;            // [2048][2048]
    const float* V = Vp + ((size_t)b * TSEQ) * DM + h * DK;   // rows stride DM

    __shared__ float As[64][13];
    __shared__ float Bs[8][68];
    const int t = threadIdx.x, tx = t & 7, ty = t >> 3;
    const int m0 = blockIdx.x * 64;
    const float* Arow = A + (size_t)(m0 + t) * TSEQ;

    float acc[8][8];
    #pragma unroll
    for (int i = 0; i < 8; ++i)
        #pragma unroll
        for (int j = 0; j < 8; ++j) acc[i][j] = 0.f;

    for (int k0 = 0; k0 < TSEQ; k0 += 8) {
        float4 a0 = *(const float4*)(Arow + k0);
        float4 a1 = *(const float4*)(Arow + k0 + 4);
        const float* vrow = V + (size_t)(k0 + (t >> 3)) * DM + (t & 7) * 8;
        float4 v0 = *(const float4*)vrow;
        float4 v1 = *(const float4*)(vrow + 4);
        __syncthreads();
        As[t][0] = a0.x; As[t][1] = a0.y; As[t][2] = a0.z; As[t][3] = a0.w;
        As[t][4] = a1.x; As[t][5] = a1.y; As[t][6] = a1.z; As[t][7] = a1.w;
        *(float4*)&Bs[t >> 3][(t & 7) * 8] = v0;
        *(float4*)&Bs[t >> 3][(t & 7) * 8 + 4] = v1;
        __syncthreads();
        #pragma unroll
        for (int kk = 0; kk < 8; ++kk) {
            float a[8];
            #pragma unroll
            for (int i = 0; i < 8; ++i) a[i] = As[ty * 8 + i][kk];
            float4 q0 = *(const float4*)&Bs[kk][tx * 8];
            float4 q1 = *(const float4*)&Bs[kk][tx * 8 + 4];
            float bb[8] = {q0.x, q0.y, q0.z, q0.w, q1.x, q1.y, q1.z, q1.w};
            #pragma unroll
            for (int i = 0; i < 8; ++i)
                #pragma unroll
                for (int j = 0; j < 8; ++j)
                    acc[i][j] = fmaf(a[i], bb[j], acc[i][j]);
        }
    }
    float* cbase = ctx + ((size_t)b * TSEQ + m0 + ty * 8) * DM + h * DK + tx * 8;
    #pragma unroll
    for (int i = 0; i < 8; ++i) {
        *(float4*)(cbase + (size_t)i * DM) =
            make_float4(acc[i][0], acc[i][1], acc[i][2], acc[i][3]);
        *(float4*)(cbase + (size_t)i * DM + 4) =
            make_float4(acc[i][4], acc[i][5], acc[i][6], acc[i][7]);
    }
}

// ---------------------------------------------------------------------------
extern "C" void kernel_launch(void* const* d_in, const int* in_sizes, int n_in,
                              void* d_out, int out_size, void* d_ws, size_t ws_size,
                              hipStream_t stream)
{
    const float* q  = (const float*)d_in[0];
    const float* k  = (const float*)d_in[1];
    const float* v  = (const float*)d_in[2];
    const float* Wq = (const float*)d_in[3];
    const float* Wk = (const float*)d_in[4];
    const float* Wv = (const float*)d_in[5];
    const float* Wo = (const float*)d_in[6];

    float* out = (float*)d_out;
    const int BT = BATCH * TSEQ;                 // 4096
    float* wts = out + (size_t)BT * DM;          // [B,H,T,T] region of d_out

    // workspace: Qp, Kp, Vp, ctx — 4 x 12.58 MB fp32
    float* Qp  = (float*)d_ws;
    float* Kp  = Qp + (size_t)BT * DM;
    float* Vp  = Kp + (size_t)BT * DM;
    float* ctx = Vp + (size_t)BT * DM;

    dim3 gproj(BT / 64, DM / 64);  // 64 x 12 = 768 blocks
    gemm_nt<<<gproj, 64, 0, stream>>>(q, Wq, Qp, DM, DM, DM, DM, 1.f);
    gemm_nt<<<gproj, 64, 0, stream>>>(k, Wk, Kp, DM, DM, DM, DM, 1.f);
    gemm_nt<<<gproj, 64, 0, stream>>>(v, Wv, Vp, DM, DM, DM, DM, 1.f);

    attn_scores<<<dim3(TSEQ / 64, TSEQ / 64, BATCH * HD), 64, 0, stream>>>(Qp, Kp, wts);
    softmax_rows<<<BATCH * HD * TSEQ, 256, 0, stream>>>(wts);
    attn_pv<<<dim3(TSEQ / 64, 1, BATCH * HD), 64, 0, stream>>>(wts, Vp, ctx);

    gemm_nt<<<gproj, 64, 0, stream>>>(ctx, Wo, out, DM, DM, DM, DM, 1.f);
}